// Round 22
// baseline (60.290 us; speedup 1.0000x reference)
//
#include <hip/hip_runtime.h>

#define S_DIM 1024
#define T_DIM 64
#define B_DIM 8
#define K_DIM 512   // KEY_DIM == QUERY_DIM
#define H_DIM 256

typedef _Float16 f16;
typedef __attribute__((ext_vector_type(4))) _Float16 f16x4;
typedef __attribute__((ext_vector_type(8))) _Float16 f16x8;
typedef __attribute__((ext_vector_type(4))) float f32x4;

__device__ __forceinline__ float fast_rcp(float x) { return __builtin_amdgcn_rcpf(x); }

__device__ __forceinline__ void gload16(const void* g, void* l) {
    __builtin_amdgcn_global_load_lds(
        (const __attribute__((address_space(1))) unsigned int*)g,
        (__attribute__((address_space(3))) unsigned int*)l, 16, 0, 0);
}

// W transpose+convert only: Wk/Wq [K][H] f32 -> WT [H][K] f16  (1 MB total)
__global__ __launch_bounds__(256) void wconv_kernel(
    const float* __restrict__ Wk, const float* __restrict__ Wq,
    f16* __restrict__ WTk, f16* __restrict__ WTq)
{
    __shared__ float tile[64][65];
    const int idx = blockIdx.x;            // 64 blocks: 2 mats x 32 tiles
    const float* W = (idx & 32) ? Wq : Wk;
    f16* WT = (idx & 32) ? WTq : WTk;
    const int t32 = idx & 31;
    const int k0 = (t32 >> 2) * 64, n0 = (t32 & 3) * 64;
    const int c = threadIdx.x & 63, r0 = threadIdx.x >> 6;
#pragma unroll
    for (int i = 0; i < 16; ++i) {
        int r = r0 + i * 4;
        tile[r][c] = W[(size_t)(k0 + r) * H_DIM + n0 + c];
    }
    __syncthreads();
#pragma unroll
    for (int i = 0; i < 16; ++i) {
        int r = r0 + i * 4;
        WT[(size_t)(n0 + r) * K_DIM + k0 + c] = (f16)tile[c][r];
    }
}

// E = exp(2*(A @ W + bias)); 32m x 64n tile, 4 waves of 16m x 32n; grid 1088.
// key half : epilogue LDS-transpose -> ktT4[b][h/4][s][4]  (h-quad interleaved).
// query half: direct tq2[b][t][h] writes.   (R17/R21-identical)
__global__ __launch_bounds__(256, 4) void proj_gemm_all(
    const float* __restrict__ key, const f16* __restrict__ WTk,
    const float* __restrict__ bk, float* __restrict__ ktT,
    const float* __restrict__ query, const f16* __restrict__ WTq,
    const float* __restrict__ bq, float* __restrict__ tq2)
{
    // [buf][ Ahi 4KB | Alo 4KB | B 8KB ]
    __shared__ __align__(16) char smem[2][16384];
    const int tid = threadIdx.x;
    const int lane = tid & 63, wid = tid >> 6;
    const int widu = __builtin_amdgcn_readfirstlane(wid);
    const int wm = (wid >> 1) * 16, wn = (wid & 1) * 32;

    // bijective XCD swizzle: 1088 = 8*136
    const int bid0 = blockIdx.x;
    const int bid = (bid0 & 7) * 136 + (bid0 >> 3);
    const bool isQ = bid >= 1024;
    const int lb = isQ ? bid - 1024 : bid;
    const size_t m0 = (size_t)(lb >> 2) * 32;
    const int n0 = (lb & 3) * 64;
    const float* A    = isQ ? query : key;
    const f16* BT     = isQ ? WTq : WTk;
    const float* bias = isQ ? bq : bk;

    // ---- B staging via global_load_lds (swizzled source, linear dest) ----
    const int o0 = tid << 4;               // [0,4096): rows 0..31
    const int o1 = o0 + 4096;              // rows 32..63
    const int row0 = o0 >> 7, kb0 = (o0 & 127) ^ ((row0 & 7) << 4);
    const int row1 = o1 >> 7, kb1 = (o1 & 127) ^ ((row1 & 7) << 4);
    const char* b_t = (const char*)(BT + (size_t)n0 * K_DIM);   // row stride 1024 B

    auto GLOADB = [&](int buf, int t) {
        const int kb = t * 128;
        char* d0 = &smem[buf][8192 + widu * 1024];
        gload16(b_t + (size_t)row0 * 1024 + kb + kb0, d0);
        gload16(b_t + (size_t)row1 * 1024 + kb + kb1, d0 + 4096);
    };

    // ---- A staging: 32 rows x 64 k f32 = 512 float4; 256 thr x 2 ----
    const float* a_base = A + m0 * K_DIM;
    float4 areg[2];
    auto ALOAD = [&](int t) {
#pragma unroll
        for (int j = 0; j < 2; ++j) {
            const int fidx = j * 256 + tid;
            const int r = fidx >> 4, c16 = fidx & 15;
            areg[j] = *(const float4*)&a_base[(size_t)r * K_DIM + t * 64 + c16 * 4];
        }
    };
    auto AWRITE = [&](int buf) {
#pragma unroll
        for (int j = 0; j < 2; ++j) {
            const int fidx = j * 256 + tid;
            const int r = fidx >> 4, c16 = fidx & 15;
            const int byt = r * 128 + ((c16 * 8) ^ ((r & 7) << 4));
            f16 h0 = (f16)areg[j].x, h1 = (f16)areg[j].y, h2 = (f16)areg[j].z, h3 = (f16)areg[j].w;
            f16x4 hi = {h0, h1, h2, h3};
            f16x4 lo = {(f16)(areg[j].x - (float)h0), (f16)(areg[j].y - (float)h1),
                        (f16)(areg[j].z - (float)h2), (f16)(areg[j].w - (float)h3)};
            *(f16x4*)&smem[buf][byt] = hi;
            *(f16x4*)&smem[buf][4096 + byt] = lo;
        }
    };

    f32x4 acc[2] = {};
    const int fr = lane & 15, fgb = (lane >> 4) << 4;

    auto COMPUTE = [&](int buf) {
#pragma unroll
        for (int kk = 0; kk < 2; ++kk) {
            const int kbyte = kk * 64 + fgb;
            const int arow = wm + fr;
            const int abyt = (arow << 7) + (kbyte ^ ((arow & 7) << 4));
            f16x8 ah = *(const f16x8*)&smem[buf][abyt];
            f16x8 al = *(const f16x8*)&smem[buf][4096 + abyt];
            const int brow0 = wn + fr, brow1 = wn + 16 + fr;
            f16x8 b0 = *(const f16x8*)&smem[buf][8192 + (brow0 << 7) + (kbyte ^ ((brow0 & 7) << 4))];
            f16x8 b1 = *(const f16x8*)&smem[buf][8192 + (brow1 << 7) + (kbyte ^ ((brow1 & 7) << 4))];
            acc[0] = __builtin_amdgcn_mfma_f32_16x16x32_f16(ah, b0, acc[0], 0, 0, 0);
            acc[1] = __builtin_amdgcn_mfma_f32_16x16x32_f16(ah, b1, acc[1], 0, 0, 0);
            acc[0] = __builtin_amdgcn_mfma_f32_16x16x32_f16(al, b0, acc[0], 0, 0, 0);
            acc[1] = __builtin_amdgcn_mfma_f32_16x16x32_f16(al, b1, acc[1], 0, 0, 0);
        }
    };

    // prologue: tile 0
    ALOAD(0);
    GLOADB(0, 0);
    AWRITE(0);
    __syncthreads();

    int buf = 0;
#pragma unroll 1
    for (int t = 0; t < 8; ++t) {
        if (t < 7) {
            ALOAD(t + 1);             // issue next-tile loads BEFORE compute
            GLOADB(buf ^ 1, t + 1);
        }
        COMPUTE(buf);
        if (t < 7) {
            AWRITE(buf ^ 1);
            __syncthreads();          // drains gloadB(buf^1); protects buf reuse
        }
        buf ^= 1;
    }

    // C/D layout (m89): col = lane&15, row = (lane>>4)*4 + reg
    const int crow = (lane >> 4) * 4, ccol = lane & 15;
    if (isQ) {
#pragma unroll
        for (int g = 0; g < 2; ++g) {
            int col = n0 + wn + g * 16 + ccol;
            float bv = bias[col];
#pragma unroll
            for (int r = 0; r < 4; ++r) {
                size_t row = m0 + wm + crow + r;
                float val = __expf(2.0f * (acc[g][r] + bv));
                tq2[((size_t)(row & 7) * T_DIM + (row >> 3)) * H_DIM + col] = val;  // [b][t][h]
            }
        }
    } else {
        // stage exp values into 8KB LDS tile [32 lrow][64 lcol]; lrow = s_off*8 + b
        float* lt = (float*)&smem[0][0];
#pragma unroll
        for (int g = 0; g < 2; ++g) {
            int lcol = wn + g * 16 + ccol;
            float bv = bias[n0 + lcol];
#pragma unroll
            for (int r = 0; r < 4; ++r) {
                int lrow = wm + crow + r;
                lt[lrow * 64 + lcol] = __expf(2.0f * (acc[g][r] + bv));
            }
        }
        __syncthreads();
        // h-quad gather: float4 = 4 consecutive h for one s (contiguous in lt).
        // ktT4[b][h/4][s][4]: float4-index = (b*64 + n0/4 + h4)*S + s.
        const int sbase = (int)(m0 >> 3);   // block's first s (4 total)
        const int n0q = n0 >> 2;
#pragma unroll
        for (int p = 0; p < 2; ++p) {
            int c = p * 256 + tid;
            int s_off = c & 3, h4 = (c >> 2) & 15, b2 = c >> 6;   // b2 in [0,8)
            float4 o = *(const float4*)&lt[(s_off * 8 + b2) * 64 + h4 * 4];
            size_t f4idx = ((size_t)b2 * 64 + n0q + h4) * S_DIM + sbase + s_off;
            *(float4*)&ktT[f4idx * 4] = o;
        }
    }
}

// Fused scores+softmax with explicit 2-deep k4 software pipeline.
// block = (b, t-pair), 1024 threads (16 waves), s = tid.
__global__ __launch_bounds__(1024) void scores_softmax_kernel(
    const float* __restrict__ ktT, const float* __restrict__ tq2,
    const float* __restrict__ v, float* __restrict__ out)
{
    __shared__ float redm[2][16], reds[2][16];
    const int tid = threadIdx.x, lane = tid & 63;
    const int wid = __builtin_amdgcn_readfirstlane(tid >> 6);   // 0..15
    const int bid = blockIdx.x;                   // [0,256)
    const int b = bid & 7;
    const int t0 = (bid >> 3) * 2;                // this block's 2 t-rows
    const int s = tid;                            // full row: s = 0..1023

    const float4* kb4 = (const float4*)ktT + (size_t)b * 64 * S_DIM + s;  // +h4*S per quad
    const float* q0p = tq2 + ((size_t)b * T_DIM + t0) * H_DIM;
    const float* q1p = q0p + H_DIM;

    float a0 = 0.f, a1 = 0.f;
    // explicit 2-deep pipeline: k4/q/v for iter i+1 issued before computing i
    float4 kcur = kb4[0];
    float4 vcur = *(const float4*)&v[0];
    float4 q0cur = *(const float4*)&q0p[0];
    float4 q1cur = *(const float4*)&q1p[0];
#pragma unroll 8
    for (int h4 = 0; h4 < H_DIM / 4; ++h4) {
        float4 knext, vnext, q0next, q1next;
        if (h4 < H_DIM / 4 - 1) {
            knext  = kb4[(size_t)(h4 + 1) * S_DIM];
            vnext  = *(const float4*)&v[(h4 + 1) * 4];
            q0next = *(const float4*)&q0p[(h4 + 1) * 4];
            q1next = *(const float4*)&q1p[(h4 + 1) * 4];
        }
        float A, B;
        A = fmaf(q0cur.x, kcur.x, 1.0f); B = fmaf(q0cur.y, kcur.y, 1.0f);
        a0 = fmaf(fmaf(vcur.x, B, vcur.y * A), fast_rcp(A * B), a0);
        A = fmaf(q0cur.z, kcur.z, 1.0f); B = fmaf(q0cur.w, kcur.w, 1.0f);
        a0 = fmaf(fmaf(vcur.z, B, vcur.w * A), fast_rcp(A * B), a0);
        A = fmaf(q1cur.x, kcur.x, 1.0f); B = fmaf(q1cur.y, kcur.y, 1.0f);
        a1 = fmaf(fmaf(vcur.x, B, vcur.y * A), fast_rcp(A * B), a1);
        A = fmaf(q1cur.z, kcur.z, 1.0f); B = fmaf(q1cur.w, kcur.w, 1.0f);
        a1 = fmaf(fmaf(vcur.z, B, vcur.w * A), fast_rcp(A * B), a1);
        kcur = knext; vcur = vnext; q0cur = q0next; q1cur = q1next;
    }
    a0 *= -2.0f;
    a1 *= -2.0f;

    // ---- block softmax over s (1024 values per t-row) ----
    float m0 = a0, m1 = a1;
#pragma unroll
    for (int mm = 32; mm >= 1; mm >>= 1) {
        m0 = fmaxf(m0, __shfl_xor(m0, mm, 64));
        m1 = fmaxf(m1, __shfl_xor(m1, mm, 64));
    }
    if (lane == 0) { redm[0][wid] = m0; redm[1][wid] = m1; }
    __syncthreads();
    m0 = redm[0][0]; m1 = redm[1][0];
#pragma unroll
    for (int i = 1; i < 16; ++i) {
        m0 = fmaxf(m0, redm[0][i]);
        m1 = fmaxf(m1, redm[1][i]);
    }

    float e0 = __expf(a0 - m0), e1 = __expf(a1 - m1);
    float s0 = e0, s1 = e1;
#pragma unroll
    for (int mm = 32; mm >= 1; mm >>= 1) {
        s0 += __shfl_xor(s0, mm, 64);
        s1 += __shfl_xor(s1, mm, 64);
    }
    if (lane == 0) { reds[0][wid] = s0; reds[1][wid] = s1; }
    __syncthreads();
    s0 = 0.f; s1 = 0.f;
#pragma unroll
    for (int i = 0; i < 16; ++i) { s0 += reds[0][i]; s1 += reds[1][i]; }

    float* o = out + ((size_t)b * T_DIM + t0) * S_DIM + s;
    o[0]     = e0 * fast_rcp(s0);
    o[S_DIM] = e1 * fast_rcp(s1);
}

extern "C" void kernel_launch(void* const* d_in, const int* in_sizes, int n_in,
                              void* d_out, int out_size, void* d_ws, size_t ws_size,
                              hipStream_t stream)
{
    const float* key   = (const float*)d_in[0];
    const float* query = (const float*)d_in[1];
    const float* Wk    = (const float*)d_in[2];
    const float* bk    = (const float*)d_in[3];
    const float* Wq    = (const float*)d_in[4];
    const float* bq    = (const float*)d_in[5];
    const float* v     = (const float*)d_in[6];
    float* out = (float*)d_out;

    float* ktT    = (float*)d_ws;                       // B*(H/4)*S*4 f32 (8.39 MB) Ek h-quad
    float* tq2    = ktT + (size_t)B_DIM * H_DIM * S_DIM;// B*T*H f32  (0.52 MB)  Eq
    f16* WTk = (f16*)(tq2 + (size_t)B_DIM * T_DIM * H_DIM);     // H*K f16
    f16* WTq = WTk + (size_t)H_DIM * K_DIM;                     // H*K f16

    wconv_kernel<<<64, 256, 0, stream>>>(Wk, Wq, WTk, WTq);
    proj_gemm_all<<<1088, 256, 0, stream>>>(key, WTk, bk, ktT, query, WTq, bq, tq2);
    scores_softmax_kernel<<<256, 1024, 0, stream>>>(ktT, tq2, v, out);
}

// Round 23
// 44.030 us; speedup vs baseline: 1.3693x; 1.3693x over previous
//
#include <hip/hip_runtime.h>

#define S_DIM 1024
#define T_DIM 64
#define B_DIM 8
#define K_DIM 512   // KEY_DIM == QUERY_DIM
#define H_DIM 256

typedef _Float16 f16;
typedef __attribute__((ext_vector_type(4))) _Float16 f16x4;
typedef __attribute__((ext_vector_type(8))) _Float16 f16x8;
typedef __attribute__((ext_vector_type(4))) float f32x4;

__device__ __forceinline__ float fast_rcp(float x) { return __builtin_amdgcn_rcpf(x); }

__device__ __forceinline__ void gload16(const void* g, void* l) {
    __builtin_amdgcn_global_load_lds(
        (const __attribute__((address_space(1))) unsigned int*)g,
        (__attribute__((address_space(3))) unsigned int*)l, 16, 0, 0);
}

// W transpose+convert only: Wk/Wq [K][H] f32 -> WT [H][K] f16  (1 MB total)
__global__ __launch_bounds__(256) void wconv_kernel(
    const float* __restrict__ Wk, const float* __restrict__ Wq,
    f16* __restrict__ WTk, f16* __restrict__ WTq)
{
    __shared__ float tile[64][65];
    const int idx = blockIdx.x;            // 64 blocks: 2 mats x 32 tiles
    const float* W = (idx & 32) ? Wq : Wk;
    f16* WT = (idx & 32) ? WTq : WTk;
    const int t32 = idx & 31;
    const int k0 = (t32 >> 2) * 64, n0 = (t32 & 3) * 64;
    const int c = threadIdx.x & 63, r0 = threadIdx.x >> 6;
#pragma unroll
    for (int i = 0; i < 16; ++i) {
        int r = r0 + i * 4;
        tile[r][c] = W[(size_t)(k0 + r) * H_DIM + n0 + c];
    }
    __syncthreads();
#pragma unroll
    for (int i = 0; i < 16; ++i) {
        int r = r0 + i * 4;
        WT[(size_t)(n0 + r) * K_DIM + k0 + c] = (f16)tile[c][r];
    }
}

// E = exp(2*(A @ W + bias)); 32m x 64n tile, 4 waves of 16m x 32n; grid 1088.
// key half : epilogue LDS-transpose -> ktT4[b][h/4][s][4]  (h-quad interleaved).
// query half: direct tq2[b][t][h] writes.   (R17/R21-identical)
__global__ __launch_bounds__(256, 4) void proj_gemm_all(
    const float* __restrict__ key, const f16* __restrict__ WTk,
    const float* __restrict__ bk, float* __restrict__ ktT,
    const float* __restrict__ query, const f16* __restrict__ WTq,
    const float* __restrict__ bq, float* __restrict__ tq2)
{
    // [buf][ Ahi 4KB | Alo 4KB | B 8KB ]
    __shared__ __align__(16) char smem[2][16384];
    const int tid = threadIdx.x;
    const int lane = tid & 63, wid = tid >> 6;
    const int widu = __builtin_amdgcn_readfirstlane(wid);
    const int wm = (wid >> 1) * 16, wn = (wid & 1) * 32;

    // bijective XCD swizzle: 1088 = 8*136
    const int bid0 = blockIdx.x;
    const int bid = (bid0 & 7) * 136 + (bid0 >> 3);
    const bool isQ = bid >= 1024;
    const int lb = isQ ? bid - 1024 : bid;
    const size_t m0 = (size_t)(lb >> 2) * 32;
    const int n0 = (lb & 3) * 64;
    const float* A    = isQ ? query : key;
    const f16* BT     = isQ ? WTq : WTk;
    const float* bias = isQ ? bq : bk;

    // ---- B staging via global_load_lds (swizzled source, linear dest) ----
    const int o0 = tid << 4;               // [0,4096): rows 0..31
    const int o1 = o0 + 4096;              // rows 32..63
    const int row0 = o0 >> 7, kb0 = (o0 & 127) ^ ((row0 & 7) << 4);
    const int row1 = o1 >> 7, kb1 = (o1 & 127) ^ ((row1 & 7) << 4);
    const char* b_t = (const char*)(BT + (size_t)n0 * K_DIM);   // row stride 1024 B

    auto GLOADB = [&](int buf, int t) {
        const int kb = t * 128;
        char* d0 = &smem[buf][8192 + widu * 1024];
        gload16(b_t + (size_t)row0 * 1024 + kb + kb0, d0);
        gload16(b_t + (size_t)row1 * 1024 + kb + kb1, d0 + 4096);
    };

    // ---- A staging: 32 rows x 64 k f32 = 512 float4; 256 thr x 2 ----
    const float* a_base = A + m0 * K_DIM;
    float4 areg[2];
    auto ALOAD = [&](int t) {
#pragma unroll
        for (int j = 0; j < 2; ++j) {
            const int fidx = j * 256 + tid;
            const int r = fidx >> 4, c16 = fidx & 15;
            areg[j] = *(const float4*)&a_base[(size_t)r * K_DIM + t * 64 + c16 * 4];
        }
    };
    auto AWRITE = [&](int buf) {
#pragma unroll
        for (int j = 0; j < 2; ++j) {
            const int fidx = j * 256 + tid;
            const int r = fidx >> 4, c16 = fidx & 15;
            const int byt = r * 128 + ((c16 * 8) ^ ((r & 7) << 4));
            f16 h0 = (f16)areg[j].x, h1 = (f16)areg[j].y, h2 = (f16)areg[j].z, h3 = (f16)areg[j].w;
            f16x4 hi = {h0, h1, h2, h3};
            f16x4 lo = {(f16)(areg[j].x - (float)h0), (f16)(areg[j].y - (float)h1),
                        (f16)(areg[j].z - (float)h2), (f16)(areg[j].w - (float)h3)};
            *(f16x4*)&smem[buf][byt] = hi;
            *(f16x4*)&smem[buf][4096 + byt] = lo;
        }
    };

    f32x4 acc[2] = {};
    const int fr = lane & 15, fgb = (lane >> 4) << 4;

    auto COMPUTE = [&](int buf) {
#pragma unroll
        for (int kk = 0; kk < 2; ++kk) {
            const int kbyte = kk * 64 + fgb;
            const int arow = wm + fr;
            const int abyt = (arow << 7) + (kbyte ^ ((arow & 7) << 4));
            f16x8 ah = *(const f16x8*)&smem[buf][abyt];
            f16x8 al = *(const f16x8*)&smem[buf][4096 + abyt];
            const int brow0 = wn + fr, brow1 = wn + 16 + fr;
            f16x8 b0 = *(const f16x8*)&smem[buf][8192 + (brow0 << 7) + (kbyte ^ ((brow0 & 7) << 4))];
            f16x8 b1 = *(const f16x8*)&smem[buf][8192 + (brow1 << 7) + (kbyte ^ ((brow1 & 7) << 4))];
            acc[0] = __builtin_amdgcn_mfma_f32_16x16x32_f16(ah, b0, acc[0], 0, 0, 0);
            acc[1] = __builtin_amdgcn_mfma_f32_16x16x32_f16(ah, b1, acc[1], 0, 0, 0);
            acc[0] = __builtin_amdgcn_mfma_f32_16x16x32_f16(al, b0, acc[0], 0, 0, 0);
            acc[1] = __builtin_amdgcn_mfma_f32_16x16x32_f16(al, b1, acc[1], 0, 0, 0);
        }
    };

    // prologue: tile 0
    ALOAD(0);
    GLOADB(0, 0);
    AWRITE(0);
    __syncthreads();

    int buf = 0;
#pragma unroll 1
    for (int t = 0; t < 8; ++t) {
        if (t < 7) {
            ALOAD(t + 1);             // issue next-tile loads BEFORE compute
            GLOADB(buf ^ 1, t + 1);
        }
        COMPUTE(buf);
        if (t < 7) {
            AWRITE(buf ^ 1);
            __syncthreads();          // drains gloadB(buf^1); protects buf reuse
        }
        buf ^= 1;
    }

    // C/D layout (m89): col = lane&15, row = (lane>>4)*4 + reg
    const int crow = (lane >> 4) * 4, ccol = lane & 15;
    if (isQ) {
#pragma unroll
        for (int g = 0; g < 2; ++g) {
            int col = n0 + wn + g * 16 + ccol;
            float bv = bias[col];
#pragma unroll
            for (int r = 0; r < 4; ++r) {
                size_t row = m0 + wm + crow + r;
                float val = __expf(2.0f * (acc[g][r] + bv));
                tq2[((size_t)(row & 7) * T_DIM + (row >> 3)) * H_DIM + col] = val;  // [b][t][h]
            }
        }
    } else {
        // stage exp values into 8KB LDS tile [32 lrow][64 lcol]; lrow = s_off*8 + b
        float* lt = (float*)&smem[0][0];
#pragma unroll
        for (int g = 0; g < 2; ++g) {
            int lcol = wn + g * 16 + ccol;
            float bv = bias[n0 + lcol];
#pragma unroll
            for (int r = 0; r < 4; ++r) {
                int lrow = wm + crow + r;
                lt[lrow * 64 + lcol] = __expf(2.0f * (acc[g][r] + bv));
            }
        }
        __syncthreads();
        // h-quad gather: float4 = 4 consecutive h for one s (contiguous in lt).
        // ktT4[b][h/4][s][4]: float4-index = (b*64 + n0/4 + h4)*S + s.
        const int sbase = (int)(m0 >> 3);   // block's first s (4 total)
        const int n0q = n0 >> 2;
#pragma unroll
        for (int p = 0; p < 2; ++p) {
            int c = p * 256 + tid;
            int s_off = c & 3, h4 = (c >> 2) & 15, b2 = c >> 6;   // b2 in [0,8)
            float4 o = *(const float4*)&lt[(s_off * 8 + b2) * 64 + h4 * 4];
            size_t f4idx = ((size_t)b2 * 64 + n0q + h4) * S_DIM + sbase + s_off;
            *(float4*)&ktT[f4idx * 4] = o;
        }
    }
}

// Fused scores+softmax: block = (b, t-pair), 1024 threads (16 waves), s = tid.
// scores_row[s] = -2 * sum_h v[h]/(Eq*Ek+1), then in-block softmax over s,
// write out[b][t][s] directly.  (R21-identical — compiler-scheduled loads)
__global__ __launch_bounds__(1024) void scores_softmax_kernel(
    const float* __restrict__ ktT, const float* __restrict__ tq2,
    const float* __restrict__ v, float* __restrict__ out)
{
    __shared__ float redm[2][16], reds[2][16];
    const int tid = threadIdx.x, lane = tid & 63;
    const int wid = __builtin_amdgcn_readfirstlane(tid >> 6);   // 0..15
    const int bid = blockIdx.x;                   // [0,256)
    const int b = bid & 7;
    const int t0 = (bid >> 3) * 2;                // this block's 2 t-rows
    const int s = tid;                            // full row: s = 0..1023

    const float4* kb4 = (const float4*)ktT + (size_t)b * 64 * S_DIM + s;  // +h4*S per quad
    const float* q0p = tq2 + ((size_t)b * T_DIM + t0) * H_DIM;
    const float* q1p = q0p + H_DIM;

    float a0 = 0.f, a1 = 0.f;
#pragma unroll 8
    for (int h4 = 0; h4 < H_DIM / 4; ++h4) {
        float4 k4 = kb4[(size_t)h4 * S_DIM];              // coalesced 16B/lane
        float4 vv = *(const float4*)&v[h4 * 4];           // uniform dwordx4
        float4 q0 = *(const float4*)&q0p[h4 * 4];
        float4 q1 = *(const float4*)&q1p[h4 * 4];
        float A, B;
        A = fmaf(q0.x, k4.x, 1.0f); B = fmaf(q0.y, k4.y, 1.0f);
        a0 = fmaf(fmaf(vv.x, B, vv.y * A), fast_rcp(A * B), a0);
        A = fmaf(q0.z, k4.z, 1.0f); B = fmaf(q0.w, k4.w, 1.0f);
        a0 = fmaf(fmaf(vv.z, B, vv.w * A), fast_rcp(A * B), a0);
        A = fmaf(q1.x, k4.x, 1.0f); B = fmaf(q1.y, k4.y, 1.0f);
        a1 = fmaf(fmaf(vv.x, B, vv.y * A), fast_rcp(A * B), a1);
        A = fmaf(q1.z, k4.z, 1.0f); B = fmaf(q1.w, k4.w, 1.0f);
        a1 = fmaf(fmaf(vv.z, B, vv.w * A), fast_rcp(A * B), a1);
    }
    a0 *= -2.0f;
    a1 *= -2.0f;

    // ---- block softmax over s (1024 values per t-row) ----
    float m0 = a0, m1 = a1;
#pragma unroll
    for (int mm = 32; mm >= 1; mm >>= 1) {
        m0 = fmaxf(m0, __shfl_xor(m0, mm, 64));
        m1 = fmaxf(m1, __shfl_xor(m1, mm, 64));
    }
    if (lane == 0) { redm[0][wid] = m0; redm[1][wid] = m1; }
    __syncthreads();
    m0 = redm[0][0]; m1 = redm[1][0];
#pragma unroll
    for (int i = 1; i < 16; ++i) {
        m0 = fmaxf(m0, redm[0][i]);
        m1 = fmaxf(m1, redm[1][i]);
    }

    float e0 = __expf(a0 - m0), e1 = __expf(a1 - m1);
    float s0 = e0, s1 = e1;
#pragma unroll
    for (int mm = 32; mm >= 1; mm >>= 1) {
        s0 += __shfl_xor(s0, mm, 64);
        s1 += __shfl_xor(s1, mm, 64);
    }
    if (lane == 0) { reds[0][wid] = s0; reds[1][wid] = s1; }
    __syncthreads();
    s0 = 0.f; s1 = 0.f;
#pragma unroll
    for (int i = 0; i < 16; ++i) { s0 += reds[0][i]; s1 += reds[1][i]; }

    float* o = out + ((size_t)b * T_DIM + t0) * S_DIM + s;
    o[0]     = e0 * fast_rcp(s0);
    o[S_DIM] = e1 * fast_rcp(s1);
}

extern "C" void kernel_launch(void* const* d_in, const int* in_sizes, int n_in,
                              void* d_out, int out_size, void* d_ws, size_t ws_size,
                              hipStream_t stream)
{
    const float* key   = (const float*)d_in[0];
    const float* query = (const float*)d_in[1];
    const float* Wk    = (const float*)d_in[2];
    const float* bk    = (const float*)d_in[3];
    const float* Wq    = (const float*)d_in[4];
    const float* bq    = (const float*)d_in[5];
    const float* v     = (const float*)d_in[6];
    float* out = (float*)d_out;

    float* ktT    = (float*)d_ws;                       // B*(H/4)*S*4 f32 (8.39 MB) Ek h-quad
    float* tq2    = ktT + (size_t)B_DIM * H_DIM * S_DIM;// B*T*H f32  (0.52 MB)  Eq
    f16* WTk = (f16*)(tq2 + (size_t)B_DIM * T_DIM * H_DIM);     // H*K f16
    f16* WTq = WTk + (size_t)H_DIM * K_DIM;                     // H*K f16

    wconv_kernel<<<64, 256, 0, stream>>>(Wk, Wq, WTk, WTq);
    proj_gemm_all<<<1088, 256, 0, stream>>>(key, WTk, bk, ktT, query, WTq, bq, tq2);
    scores_softmax_kernel<<<256, 1024, 0, stream>>>(ktT, tq2, v, out);
}

// Round 24
// 43.092 us; speedup vs baseline: 1.3991x; 1.0218x over previous
//
#include <hip/hip_runtime.h>

#define S_DIM 1024
#define T_DIM 64
#define B_DIM 8
#define K_DIM 512   // KEY_DIM == QUERY_DIM
#define H_DIM 256

typedef _Float16 f16;
typedef __attribute__((ext_vector_type(4))) _Float16 f16x4;
typedef __attribute__((ext_vector_type(8))) _Float16 f16x8;
typedef __attribute__((ext_vector_type(4))) float f32x4;

__device__ __forceinline__ float fast_rcp(float x) { return __builtin_amdgcn_rcpf(x); }

__device__ __forceinline__ void gload16(const void* g, void* l) {
    __builtin_amdgcn_global_load_lds(
        (const __attribute__((address_space(1))) unsigned int*)g,
        (__attribute__((address_space(3))) unsigned int*)l, 16, 0, 0);
}

// W transpose+convert only: Wk/Wq [K][H] f32 -> WT [H][K] f16  (1 MB total)
__global__ __launch_bounds__(256) void wconv_kernel(
    const float* __restrict__ Wk, const float* __restrict__ Wq,
    f16* __restrict__ WTk, f16* __restrict__ WTq)
{
    __shared__ float tile[64][65];
    const int idx = blockIdx.x;            // 64 blocks: 2 mats x 32 tiles
    const float* W = (idx & 32) ? Wq : Wk;
    f16* WT = (idx & 32) ? WTq : WTk;
    const int t32 = idx & 31;
    const int k0 = (t32 >> 2) * 64, n0 = (t32 & 3) * 64;
    const int c = threadIdx.x & 63, r0 = threadIdx.x >> 6;
#pragma unroll
    for (int i = 0; i < 16; ++i) {
        int r = r0 + i * 4;
        tile[r][c] = W[(size_t)(k0 + r) * H_DIM + n0 + c];
    }
    __syncthreads();
#pragma unroll
    for (int i = 0; i < 16; ++i) {
        int r = r0 + i * 4;
        WT[(size_t)(n0 + r) * K_DIM + k0 + c] = (f16)tile[c][r];
    }
}

// E = exp(2*(A @ W + bias)); 64x64 tile (R13/R14-measured 9.5us structure),
// BK=64, 4 waves (2x2 of 32x32), grid 544, 48KB LDS (3 blk/CU).
// key half : epilogue LDS-stage [b*8+s_off][68] -> h-quad gather ->
//            ktT4[b][h/4][s][4] (128B-contiguous store groups, conflict-free reads).
// query half: direct tq2[b][t][h] writes.
__global__ __launch_bounds__(256, 3) void proj_gemm_all(
    const float* __restrict__ key, const f16* __restrict__ WTk,
    const float* __restrict__ bk, float* __restrict__ ktT,
    const float* __restrict__ query, const f16* __restrict__ WTq,
    const float* __restrict__ bq, float* __restrict__ tq2)
{
    __shared__ __align__(16) char smem[2][3][8192];   // [buf][Ahi,Alo,B][64 rows x 128 B]
    const int tid = threadIdx.x;
    const int lane = tid & 63, wid = tid >> 6;
    const int widu = __builtin_amdgcn_readfirstlane(wid);
    const int wm = (wid >> 1) * 32, wn = (wid & 1) * 32;

    const int bid0 = blockIdx.x;
    const int bid = (bid0 & 7) * 68 + (bid0 >> 3);   // bijective: 544 = 8*68
    const bool isQ = bid >= 512;
    const int lb = isQ ? bid - 512 : bid;
    const size_t m0 = (size_t)(lb >> 2) * 64;
    const int n0 = (lb & 3) * 64;
    const float* A    = isQ ? query : key;
    const f16* BT     = isQ ? WTq : WTk;
    const float* bias = isQ ? bq : bk;

    // ---- B staging via global_load_lds (swizzled source, linear dest) ----
    const int o0 = wid * 1024 + (lane << 4);
    const int o1 = o0 + 4096;
    const int row0 = o0 >> 7, kb0 = (o0 & 127) ^ ((row0 & 7) << 4);
    const int row1 = o1 >> 7, kb1 = (o1 & 127) ^ ((row1 & 7) << 4);
    const char* b_t = (const char*)(BT + (size_t)n0 * K_DIM);   // row stride 1024 B

    auto GLOADB = [&](int buf, int t) {
        const int kb = t * 128;
        char* d0 = &smem[buf][2][widu * 1024];
        gload16(b_t + (size_t)row0 * 1024 + kb + kb0, d0);
        gload16(b_t + (size_t)row1 * 1024 + kb + kb1, d0 + 4096);
    };

    // ---- A staging: global f32 -> regs -> fp16 hi/lo -> swizzled ds_write ----
    const float* a_base = A + m0 * K_DIM;
    float4 areg[4];
    auto ALOAD = [&](int t) {
#pragma unroll
        for (int j = 0; j < 4; ++j) {
            const int fidx = j * 256 + tid;
            const int r = fidx >> 4, c16 = fidx & 15;
            areg[j] = *(const float4*)&a_base[(size_t)r * K_DIM + t * 64 + c16 * 4];
        }
    };
    auto AWRITE = [&](int buf) {
#pragma unroll
        for (int j = 0; j < 4; ++j) {
            const int fidx = j * 256 + tid;
            const int r = fidx >> 4, c16 = fidx & 15;
            const int byt = r * 128 + ((c16 * 8) ^ ((r & 7) << 4));
            f16 h0 = (f16)areg[j].x, h1 = (f16)areg[j].y, h2 = (f16)areg[j].z, h3 = (f16)areg[j].w;
            f16x4 hi = {h0, h1, h2, h3};
            f16x4 lo = {(f16)(areg[j].x - (float)h0), (f16)(areg[j].y - (float)h1),
                        (f16)(areg[j].z - (float)h2), (f16)(areg[j].w - (float)h3)};
            *(f16x4*)&smem[buf][0][byt] = hi;
            *(f16x4*)&smem[buf][1][byt] = lo;
        }
    };

    f32x4 acc[2][2] = {};
    const int fr = lane & 15, fgb = (lane >> 4) << 4;

    auto COMPUTE = [&](int buf) {
#pragma unroll
        for (int kk = 0; kk < 2; ++kk) {
            const int kbyte = kk * 64 + fgb;
            auto ld = [&](int arr, int row) -> f16x8 {
                int byt = ((row << 7) + kbyte) ^ ((row & 7) << 4);
                return *(const f16x8*)&smem[buf][arr][byt];
            };
            f16x8 ah0 = ld(0, wm + fr),      ah1 = ld(0, wm + 16 + fr);
            f16x8 al0 = ld(1, wm + fr),      al1 = ld(1, wm + 16 + fr);
            f16x8 b0  = ld(2, wn + fr),      b1  = ld(2, wn + 16 + fr);
            acc[0][0] = __builtin_amdgcn_mfma_f32_16x16x32_f16(ah0, b0, acc[0][0], 0, 0, 0);
            acc[0][1] = __builtin_amdgcn_mfma_f32_16x16x32_f16(ah0, b1, acc[0][1], 0, 0, 0);
            acc[1][0] = __builtin_amdgcn_mfma_f32_16x16x32_f16(ah1, b0, acc[1][0], 0, 0, 0);
            acc[1][1] = __builtin_amdgcn_mfma_f32_16x16x32_f16(ah1, b1, acc[1][1], 0, 0, 0);
            acc[0][0] = __builtin_amdgcn_mfma_f32_16x16x32_f16(al0, b0, acc[0][0], 0, 0, 0);
            acc[0][1] = __builtin_amdgcn_mfma_f32_16x16x32_f16(al0, b1, acc[0][1], 0, 0, 0);
            acc[1][0] = __builtin_amdgcn_mfma_f32_16x16x32_f16(al1, b0, acc[1][0], 0, 0, 0);
            acc[1][1] = __builtin_amdgcn_mfma_f32_16x16x32_f16(al1, b1, acc[1][1], 0, 0, 0);
        }
    };

    ALOAD(0);
    GLOADB(0, 0);
    AWRITE(0);
    __syncthreads();

    int buf = 0;
#pragma unroll 1
    for (int t = 0; t < 8; ++t) {
        if (t < 7) { ALOAD(t + 1); GLOADB(buf ^ 1, t + 1); }
        COMPUTE(buf);
        if (t < 7) { AWRITE(buf ^ 1); __syncthreads(); }
        buf ^= 1;
    }

    // C/D layout (m89): col = lane&15, row = (lane>>4)*4 + reg
    const int crow = (lane >> 4) * 4, ccol = lane & 15;
    if (isQ) {
#pragma unroll
        for (int f = 0; f < 2; ++f)
#pragma unroll
            for (int g = 0; g < 2; ++g) {
                int col = n0 + wn + g * 16 + ccol;
                float bv = bias[col];
#pragma unroll
                for (int r = 0; r < 4; ++r) {
                    size_t row = m0 + wm + f * 16 + crow + r;
                    float val = __expf(2.0f * (acc[f][g][r] + bv));
                    tq2[((size_t)(row & 7) * T_DIM + (row >> 3)) * H_DIM + col] = val;  // [b][t][h]
                }
            }
    } else {
        // stage into lt[b*8+s_off][68] (17.4 KB in smem[0], free after t=6 barrier;
        // t=7 reads smem[1] only).  Pitch 68 floats = 272B: 16B-aligned, and the
        // h-quad gather (consecutive lanes = s_off) reads stride-68 -> banks 4i%32,
        // conflict-free ds_read_b128.
        float* lt = (float*)&smem[0][0][0];
#pragma unroll
        for (int f = 0; f < 2; ++f)
#pragma unroll
            for (int g = 0; g < 2; ++g) {
                int lcol = wn + g * 16 + ccol;
                float bv = bias[n0 + lcol];
#pragma unroll
                for (int r = 0; r < 4; ++r) {
                    int rr = wm + f * 16 + crow + r;         // row in tile: rr = s_off*8 + b
                    lt[((rr & 7) * 8 + (rr >> 3)) * 68 + lcol] = __expf(2.0f * (acc[f][g][r] + bv));
                }
            }
        __syncthreads();
        // h-quad gather: float4 = 4 consecutive h at one s; 1024 chunks, 4/thread.
        // ktT4[b][h/4][s][4]: f4idx = (b*64 + n0/4 + h4)*S + sbase + s_off.
        // 8-lane groups (s_off 0..7) -> 128B-contiguous global stores.
        const int sbase = (int)(m0 >> 3);   // block's first s (8 total)
        const int n0q = n0 >> 2;
#pragma unroll
        for (int p = 0; p < 4; ++p) {
            int c = p * 256 + tid;
            int s_off = c & 7, h4 = (c >> 3) & 15, b2 = c >> 7;   // b2 in [0,8)
            float4 o = *(const float4*)&lt[(b2 * 8 + s_off) * 68 + h4 * 4];
            size_t f4idx = ((size_t)b2 * 64 + n0q + h4) * S_DIM + sbase + s_off;
            *(float4*)&ktT[f4idx * 4] = o;
        }
    }
}

// Fused scores+softmax: block = (b, t-pair), 1024 threads (16 waves), s = tid.
// scores_row[s] = -2 * sum_h v[h]/(Eq*Ek+1), then in-block softmax over s,
// write out[b][t][s] directly.  (R21/R23-identical)
__global__ __launch_bounds__(1024) void scores_softmax_kernel(
    const float* __restrict__ ktT, const float* __restrict__ tq2,
    const float* __restrict__ v, float* __restrict__ out)
{
    __shared__ float redm[2][16], reds[2][16];
    const int tid = threadIdx.x, lane = tid & 63;
    const int wid = __builtin_amdgcn_readfirstlane(tid >> 6);   // 0..15
    const int bid = blockIdx.x;                   // [0,256)
    const int b = bid & 7;
    const int t0 = (bid >> 3) * 2;                // this block's 2 t-rows
    const int s = tid;                            // full row: s = 0..1023

    const float4* kb4 = (const float4*)ktT + (size_t)b * 64 * S_DIM + s;  // +h4*S per quad
    const float* q0p = tq2 + ((size_t)b * T_DIM + t0) * H_DIM;
    const float* q1p = q0p + H_DIM;

    float a0 = 0.f, a1 = 0.f;
#pragma unroll 8
    for (int h4 = 0; h4 < H_DIM / 4; ++h4) {
        float4 k4 = kb4[(size_t)h4 * S_DIM];              // coalesced 16B/lane
        float4 vv = *(const float4*)&v[h4 * 4];           // uniform dwordx4
        float4 q0 = *(const float4*)&q0p[h4 * 4];
        float4 q1 = *(const float4*)&q1p[h4 * 4];
        float A, B;
        A = fmaf(q0.x, k4.x, 1.0f); B = fmaf(q0.y, k4.y, 1.0f);
        a0 = fmaf(fmaf(vv.x, B, vv.y * A), fast_rcp(A * B), a0);
        A = fmaf(q0.z, k4.z, 1.0f); B = fmaf(q0.w, k4.w, 1.0f);
        a0 = fmaf(fmaf(vv.z, B, vv.w * A), fast_rcp(A * B), a0);
        A = fmaf(q1.x, k4.x, 1.0f); B = fmaf(q1.y, k4.y, 1.0f);
        a1 = fmaf(fmaf(vv.x, B, vv.y * A), fast_rcp(A * B), a1);
        A = fmaf(q1.z, k4.z, 1.0f); B = fmaf(q1.w, k4.w, 1.0f);
        a1 = fmaf(fmaf(vv.z, B, vv.w * A), fast_rcp(A * B), a1);
    }
    a0 *= -2.0f;
    a1 *= -2.0f;

    // ---- block softmax over s (1024 values per t-row) ----
    float m0 = a0, m1 = a1;
#pragma unroll
    for (int mm = 32; mm >= 1; mm >>= 1) {
        m0 = fmaxf(m0, __shfl_xor(m0, mm, 64));
        m1 = fmaxf(m1, __shfl_xor(m1, mm, 64));
    }
    if (lane == 0) { redm[0][wid] = m0; redm[1][wid] = m1; }
    __syncthreads();
    m0 = redm[0][0]; m1 = redm[1][0];
#pragma unroll
    for (int i = 1; i < 16; ++i) {
        m0 = fmaxf(m0, redm[0][i]);
        m1 = fmaxf(m1, redm[1][i]);
    }

    float e0 = __expf(a0 - m0), e1 = __expf(a1 - m1);
    float s0 = e0, s1 = e1;
#pragma unroll
    for (int mm = 32; mm >= 1; mm >>= 1) {
        s0 += __shfl_xor(s0, mm, 64);
        s1 += __shfl_xor(s1, mm, 64);
    }
    if (lane == 0) { reds[0][wid] = s0; reds[1][wid] = s1; }
    __syncthreads();
    s0 = 0.f; s1 = 0.f;
#pragma unroll
    for (int i = 0; i < 16; ++i) { s0 += reds[0][i]; s1 += reds[1][i]; }

    float* o = out + ((size_t)b * T_DIM + t0) * S_DIM + s;
    o[0]     = e0 * fast_rcp(s0);
    o[S_DIM] = e1 * fast_rcp(s1);
}

extern "C" void kernel_launch(void* const* d_in, const int* in_sizes, int n_in,
                              void* d_out, int out_size, void* d_ws, size_t ws_size,
                              hipStream_t stream)
{
    const float* key   = (const float*)d_in[0];
    const float* query = (const float*)d_in[1];
    const float* Wk    = (const float*)d_in[2];
    const float* bk    = (const float*)d_in[3];
    const float* Wq    = (const float*)d_in[4];
    const float* bq    = (const float*)d_in[5];
    const float* v     = (const float*)d_in[6];
    float* out = (float*)d_out;

    float* ktT    = (float*)d_ws;                       // B*(H/4)*S*4 f32 (8.39 MB) Ek h-quad
    float* tq2    = ktT + (size_t)B_DIM * H_DIM * S_DIM;// B*T*H f32  (0.52 MB)  Eq
    f16* WTk = (f16*)(tq2 + (size_t)B_DIM * T_DIM * H_DIM);     // H*K f16
    f16* WTq = WTk + (size_t)H_DIM * K_DIM;                     // H*K f16

    wconv_kernel<<<64, 256, 0, stream>>>(Wk, Wq, WTk, WTq);
    proj_gemm_all<<<544, 256, 0, stream>>>(key, WTk, bk, ktT, query, WTq, bq, tq2);
    scores_softmax_kernel<<<256, 1024, 0, stream>>>(ktT, tq2, v, out);
}

// Round 25
// 42.323 us; speedup vs baseline: 1.4245x; 1.0182x over previous
//
#include <hip/hip_runtime.h>

#define S_DIM 1024
#define T_DIM 64
#define B_DIM 8
#define K_DIM 512   // KEY_DIM == QUERY_DIM
#define H_DIM 256

typedef _Float16 f16;
typedef __attribute__((ext_vector_type(4))) _Float16 f16x4;
typedef __attribute__((ext_vector_type(8))) _Float16 f16x8;
typedef __attribute__((ext_vector_type(4))) float f32x4;

__device__ __forceinline__ float fast_rcp(float x) { return __builtin_amdgcn_rcpf(x); }

__device__ __forceinline__ void gload16(const void* g, void* l) {
    __builtin_amdgcn_global_load_lds(
        (const __attribute__((address_space(1))) unsigned int*)g,
        (__attribute__((address_space(3))) unsigned int*)l, 16, 0, 0);
}

// W transpose+convert only: Wk/Wq [K][H] f32 -> WT [H][K] f16  (1 MB total)
__global__ __launch_bounds__(256) void wconv_kernel(
    const float* __restrict__ Wk, const float* __restrict__ Wq,
    f16* __restrict__ WTk, f16* __restrict__ WTq)
{
    __shared__ float tile[64][65];
    const int idx = blockIdx.x;            // 64 blocks: 2 mats x 32 tiles
    const float* W = (idx & 32) ? Wq : Wk;
    f16* WT = (idx & 32) ? WTq : WTk;
    const int t32 = idx & 31;
    const int k0 = (t32 >> 2) * 64, n0 = (t32 & 3) * 64;
    const int c = threadIdx.x & 63, r0 = threadIdx.x >> 6;
#pragma unroll
    for (int i = 0; i < 16; ++i) {
        int r = r0 + i * 4;
        tile[r][c] = W[(size_t)(k0 + r) * H_DIM + n0 + c];
    }
    __syncthreads();
#pragma unroll
    for (int i = 0; i < 16; ++i) {
        int r = r0 + i * 4;
        WT[(size_t)(n0 + r) * K_DIM + k0 + c] = (f16)tile[c][r];
    }
}

// E = exp(2*(A @ W + bias)); 64x64 tile, BK=64, 4 waves (2x2 of 32x32), grid 544.
// key half : epilogue LDS-stage [b*8+s_off][68] -> h-quad gather ->
//            ktT4[b][h/4][s][4].  query half: direct tq2[b][t][h].  (R24-identical)
__global__ __launch_bounds__(256, 3) void proj_gemm_all(
    const float* __restrict__ key, const f16* __restrict__ WTk,
    const float* __restrict__ bk, float* __restrict__ ktT,
    const float* __restrict__ query, const f16* __restrict__ WTq,
    const float* __restrict__ bq, float* __restrict__ tq2)
{
    __shared__ __align__(16) char smem[2][3][8192];   // [buf][Ahi,Alo,B][64 rows x 128 B]
    const int tid = threadIdx.x;
    const int lane = tid & 63, wid = tid >> 6;
    const int widu = __builtin_amdgcn_readfirstlane(wid);
    const int wm = (wid >> 1) * 32, wn = (wid & 1) * 32;

    const int bid0 = blockIdx.x;
    const int bid = (bid0 & 7) * 68 + (bid0 >> 3);   // bijective: 544 = 8*68
    const bool isQ = bid >= 512;
    const int lb = isQ ? bid - 512 : bid;
    const size_t m0 = (size_t)(lb >> 2) * 64;
    const int n0 = (lb & 3) * 64;
    const float* A    = isQ ? query : key;
    const f16* BT     = isQ ? WTq : WTk;
    const float* bias = isQ ? bq : bk;

    // ---- B staging via global_load_lds (swizzled source, linear dest) ----
    const int o0 = wid * 1024 + (lane << 4);
    const int o1 = o0 + 4096;
    const int row0 = o0 >> 7, kb0 = (o0 & 127) ^ ((row0 & 7) << 4);
    const int row1 = o1 >> 7, kb1 = (o1 & 127) ^ ((row1 & 7) << 4);
    const char* b_t = (const char*)(BT + (size_t)n0 * K_DIM);   // row stride 1024 B

    auto GLOADB = [&](int buf, int t) {
        const int kb = t * 128;
        char* d0 = &smem[buf][2][widu * 1024];
        gload16(b_t + (size_t)row0 * 1024 + kb + kb0, d0);
        gload16(b_t + (size_t)row1 * 1024 + kb + kb1, d0 + 4096);
    };

    // ---- A staging: global f32 -> regs -> fp16 hi/lo -> swizzled ds_write ----
    const float* a_base = A + m0 * K_DIM;
    float4 areg[4];
    auto ALOAD = [&](int t) {
#pragma unroll
        for (int j = 0; j < 4; ++j) {
            const int fidx = j * 256 + tid;
            const int r = fidx >> 4, c16 = fidx & 15;
            areg[j] = *(const float4*)&a_base[(size_t)r * K_DIM + t * 64 + c16 * 4];
        }
    };
    auto AWRITE = [&](int buf) {
#pragma unroll
        for (int j = 0; j < 4; ++j) {
            const int fidx = j * 256 + tid;
            const int r = fidx >> 4, c16 = fidx & 15;
            const int byt = r * 128 + ((c16 * 8) ^ ((r & 7) << 4));
            f16 h0 = (f16)areg[j].x, h1 = (f16)areg[j].y, h2 = (f16)areg[j].z, h3 = (f16)areg[j].w;
            f16x4 hi = {h0, h1, h2, h3};
            f16x4 lo = {(f16)(areg[j].x - (float)h0), (f16)(areg[j].y - (float)h1),
                        (f16)(areg[j].z - (float)h2), (f16)(areg[j].w - (float)h3)};
            *(f16x4*)&smem[buf][0][byt] = hi;
            *(f16x4*)&smem[buf][1][byt] = lo;
        }
    };

    f32x4 acc[2][2] = {};
    const int fr = lane & 15, fgb = (lane >> 4) << 4;

    auto COMPUTE = [&](int buf) {
#pragma unroll
        for (int kk = 0; kk < 2; ++kk) {
            const int kbyte = kk * 64 + fgb;
            auto ld = [&](int arr, int row) -> f16x8 {
                int byt = ((row << 7) + kbyte) ^ ((row & 7) << 4);
                return *(const f16x8*)&smem[buf][arr][byt];
            };
            f16x8 ah0 = ld(0, wm + fr),      ah1 = ld(0, wm + 16 + fr);
            f16x8 al0 = ld(1, wm + fr),      al1 = ld(1, wm + 16 + fr);
            f16x8 b0  = ld(2, wn + fr),      b1  = ld(2, wn + 16 + fr);
            acc[0][0] = __builtin_amdgcn_mfma_f32_16x16x32_f16(ah0, b0, acc[0][0], 0, 0, 0);
            acc[0][1] = __builtin_amdgcn_mfma_f32_16x16x32_f16(ah0, b1, acc[0][1], 0, 0, 0);
            acc[1][0] = __builtin_amdgcn_mfma_f32_16x16x32_f16(ah1, b0, acc[1][0], 0, 0, 0);
            acc[1][1] = __builtin_amdgcn_mfma_f32_16x16x32_f16(ah1, b1, acc[1][1], 0, 0, 0);
            acc[0][0] = __builtin_amdgcn_mfma_f32_16x16x32_f16(al0, b0, acc[0][0], 0, 0, 0);
            acc[0][1] = __builtin_amdgcn_mfma_f32_16x16x32_f16(al0, b1, acc[0][1], 0, 0, 0);
            acc[1][0] = __builtin_amdgcn_mfma_f32_16x16x32_f16(al1, b0, acc[1][0], 0, 0, 0);
            acc[1][1] = __builtin_amdgcn_mfma_f32_16x16x32_f16(al1, b1, acc[1][1], 0, 0, 0);
        }
    };

    ALOAD(0);
    GLOADB(0, 0);
    AWRITE(0);
    __syncthreads();

    int buf = 0;
#pragma unroll 1
    for (int t = 0; t < 8; ++t) {
        if (t < 7) { ALOAD(t + 1); GLOADB(buf ^ 1, t + 1); }
        COMPUTE(buf);
        if (t < 7) { AWRITE(buf ^ 1); __syncthreads(); }
        buf ^= 1;
    }

    // C/D layout (m89): col = lane&15, row = (lane>>4)*4 + reg
    const int crow = (lane >> 4) * 4, ccol = lane & 15;
    if (isQ) {
#pragma unroll
        for (int f = 0; f < 2; ++f)
#pragma unroll
            for (int g = 0; g < 2; ++g) {
                int col = n0 + wn + g * 16 + ccol;
                float bv = bias[col];
#pragma unroll
                for (int r = 0; r < 4; ++r) {
                    size_t row = m0 + wm + f * 16 + crow + r;
                    float val = __expf(2.0f * (acc[f][g][r] + bv));
                    tq2[((size_t)(row & 7) * T_DIM + (row >> 3)) * H_DIM + col] = val;  // [b][t][h]
                }
            }
    } else {
        // stage into lt[b*8+s_off][68]; pitch 272B -> conflict-free gather reads
        float* lt = (float*)&smem[0][0][0];
#pragma unroll
        for (int f = 0; f < 2; ++f)
#pragma unroll
            for (int g = 0; g < 2; ++g) {
                int lcol = wn + g * 16 + ccol;
                float bv = bias[n0 + lcol];
#pragma unroll
                for (int r = 0; r < 4; ++r) {
                    int rr = wm + f * 16 + crow + r;         // rr = s_off*8 + b
                    lt[((rr & 7) * 8 + (rr >> 3)) * 68 + lcol] = __expf(2.0f * (acc[f][g][r] + bv));
                }
            }
        __syncthreads();
        // h-quad gather -> ktT4[b][h/4][s][4]; 8-lane 128B-contiguous store groups
        const int sbase = (int)(m0 >> 3);
        const int n0q = n0 >> 2;
#pragma unroll
        for (int p = 0; p < 4; ++p) {
            int c = p * 256 + tid;
            int s_off = c & 7, h4 = (c >> 3) & 15, b2 = c >> 7;
            float4 o = *(const float4*)&lt[(b2 * 8 + s_off) * 68 + h4 * 4];
            size_t f4idx = ((size_t)b2 * 64 + n0q + h4) * S_DIM + sbase + s_off;
            *(float4*)&ktT[f4idx * 4] = o;
        }
    }
}

// Fused scores+softmax: block = (b, t-pair), 1024 threads (16 waves), s = tid.
// 4-WAY rcp pairing: v1/A+v2/B+v3/C+v4/D = (n1*CD + n2*AB)/(AB*CD)
// -> 13 VALU + 1 trans per t per 4h (was 12 VALU + 2 trans).
// AB*CD < e^66 worst-case (qp+kp ~ N(0,sqrt2), max ~8.2 over 134M draws) — no overflow.
__global__ __launch_bounds__(1024) void scores_softmax_kernel(
    const float* __restrict__ ktT, const float* __restrict__ tq2,
    const float* __restrict__ v, float* __restrict__ out)
{
    __shared__ float redm[2][16], reds[2][16];
    const int tid = threadIdx.x, lane = tid & 63;
    const int wid = __builtin_amdgcn_readfirstlane(tid >> 6);   // 0..15
    const int bid = blockIdx.x;                   // [0,256)
    const int b = bid & 7;
    const int t0 = (bid >> 3) * 2;                // this block's 2 t-rows
    const int s = tid;                            // full row: s = 0..1023

    const float4* kb4 = (const float4*)ktT + (size_t)b * 64 * S_DIM + s;  // +h4*S per quad
    const float* q0p = tq2 + ((size_t)b * T_DIM + t0) * H_DIM;
    const float* q1p = q0p + H_DIM;

    float a0 = 0.f, a1 = 0.f;
#pragma unroll 8
    for (int h4 = 0; h4 < H_DIM / 4; ++h4) {
        float4 k4 = kb4[(size_t)h4 * S_DIM];              // coalesced 16B/lane
        float4 vv = *(const float4*)&v[h4 * 4];           // uniform dwordx4
        float4 q0 = *(const float4*)&q0p[h4 * 4];
        float4 q1 = *(const float4*)&q1p[h4 * 4];
        float A, B, C, D, AB, CD, n1, n2;
#define SC4(qq, aa) \
        A = fmaf(qq.x, k4.x, 1.0f); B = fmaf(qq.y, k4.y, 1.0f); \
        C = fmaf(qq.z, k4.z, 1.0f); D = fmaf(qq.w, k4.w, 1.0f); \
        AB = A * B; CD = C * D; \
        n1 = fmaf(vv.x, B, vv.y * A); \
        n2 = fmaf(vv.z, D, vv.w * C); \
        aa = fmaf(fmaf(n1, CD, n2 * AB), fast_rcp(AB * CD), aa);
        SC4(q0, a0)
        SC4(q1, a1)
#undef SC4
    }
    a0 *= -2.0f;
    a1 *= -2.0f;

    // ---- block softmax over s (1024 values per t-row) ----
    float m0 = a0, m1 = a1;
#pragma unroll
    for (int mm = 32; mm >= 1; mm >>= 1) {
        m0 = fmaxf(m0, __shfl_xor(m0, mm, 64));
        m1 = fmaxf(m1, __shfl_xor(m1, mm, 64));
    }
    if (lane == 0) { redm[0][wid] = m0; redm[1][wid] = m1; }
    __syncthreads();
    m0 = redm[0][0]; m1 = redm[1][0];
#pragma unroll
    for (int i = 1; i < 16; ++i) {
        m0 = fmaxf(m0, redm[0][i]);
        m1 = fmaxf(m1, redm[1][i]);
    }

    float e0 = __expf(a0 - m0), e1 = __expf(a1 - m1);
    float s0 = e0, s1 = e1;
#pragma unroll
    for (int mm = 32; mm >= 1; mm >>= 1) {
        s0 += __shfl_xor(s0, mm, 64);
        s1 += __shfl_xor(s1, mm, 64);
    }
    if (lane == 0) { reds[0][wid] = s0; reds[1][wid] = s1; }
    __syncthreads();
    s0 = 0.f; s1 = 0.f;
#pragma unroll
    for (int i = 0; i < 16; ++i) { s0 += reds[0][i]; s1 += reds[1][i]; }

    float* o = out + ((size_t)b * T_DIM + t0) * S_DIM + s;
    o[0]     = e0 * fast_rcp(s0);
    o[S_DIM] = e1 * fast_rcp(s1);
}

extern "C" void kernel_launch(void* const* d_in, const int* in_sizes, int n_in,
                              void* d_out, int out_size, void* d_ws, size_t ws_size,
                              hipStream_t stream)
{
    const float* key   = (const float*)d_in[0];
    const float* query = (const float*)d_in[1];
    const float* Wk    = (const float*)d_in[2];
    const float* bk    = (const float*)d_in[3];
    const float* Wq    = (const float*)d_in[4];
    const float* bq    = (const float*)d_in[5];
    const float* v     = (const float*)d_in[6];
    float* out = (float*)d_out;

    float* ktT    = (float*)d_ws;                       // B*(H/4)*S*4 f32 (8.39 MB) Ek h-quad
    float* tq2    = ktT + (size_t)B_DIM * H_DIM * S_DIM;// B*T*H f32  (0.52 MB)  Eq
    f16* WTk = (f16*)(tq2 + (size_t)B_DIM * T_DIM * H_DIM);     // H*K f16
    f16* WTq = WTk + (size_t)H_DIM * K_DIM;                     // H*K f16

    wconv_kernel<<<64, 256, 0, stream>>>(Wk, Wq, WTk, WTq);
    proj_gemm_all<<<544, 256, 0, stream>>>(key, WTk, bk, ktT, query, WTq, bq, tq2);
    scores_softmax_kernel<<<256, 1024, 0, stream>>>(ktT, tq2, v, out);
}

// Round 26
// 42.096 us; speedup vs baseline: 1.4322x; 1.0054x over previous
//
#include <hip/hip_runtime.h>

#define S_DIM 1024
#define T_DIM 64
#define B_DIM 8
#define K_DIM 512   // KEY_DIM == QUERY_DIM
#define H_DIM 256

typedef _Float16 f16;
typedef __attribute__((ext_vector_type(4))) _Float16 f16x4;
typedef __attribute__((ext_vector_type(8))) _Float16 f16x8;
typedef __attribute__((ext_vector_type(4))) float f32x4;

__device__ __forceinline__ float fast_rcp(float x) { return __builtin_amdgcn_rcpf(x); }

__device__ __forceinline__ void gload16(const void* g, void* l) {
    __builtin_amdgcn_global_load_lds(
        (const __attribute__((address_space(1))) unsigned int*)g,
        (__attribute__((address_space(3))) unsigned int*)l, 16, 0, 0);
}

// W transpose+convert only: Wk/Wq [K][H] f32 -> WT [H][K] f16  (1 MB total)
__global__ __launch_bounds__(256) void wconv_kernel(
    const float* __restrict__ Wk, const float* __restrict__ Wq,
    f16* __restrict__ WTk, f16* __restrict__ WTq)
{
    __shared__ float tile[64][65];
    const int idx = blockIdx.x;            // 64 blocks: 2 mats x 32 tiles
    const float* W = (idx & 32) ? Wq : Wk;
    f16* WT = (idx & 32) ? WTq : WTk;
    const int t32 = idx & 31;
    const int k0 = (t32 >> 2) * 64, n0 = (t32 & 3) * 64;
    const int c = threadIdx.x & 63, r0 = threadIdx.x >> 6;
#pragma unroll
    for (int i = 0; i < 16; ++i) {
        int r = r0 + i * 4;
        tile[r][c] = W[(size_t)(k0 + r) * H_DIM + n0 + c];
    }
    __syncthreads();
#pragma unroll
    for (int i = 0; i < 16; ++i) {
        int r = r0 + i * 4;
        WT[(size_t)(n0 + r) * K_DIM + k0 + c] = (f16)tile[c][r];
    }
}

// E = exp(2*(A @ W + bias)); 64x64 tile, BK=64, 4 waves (2x2 of 32x32), grid 544.
// key half : epilogue LDS-stage [b*8+s_off][68] -> h-quad gather ->
//            ktT4[b][h/4][s][4].  query half: direct tq2[b][t][h].  (R24-identical)
__global__ __launch_bounds__(256, 3) void proj_gemm_all(
    const float* __restrict__ key, const f16* __restrict__ WTk,
    const float* __restrict__ bk, float* __restrict__ ktT,
    const float* __restrict__ query, const f16* __restrict__ WTq,
    const float* __restrict__ bq, float* __restrict__ tq2)
{
    __shared__ __align__(16) char smem[2][3][8192];   // [buf][Ahi,Alo,B][64 rows x 128 B]
    const int tid = threadIdx.x;
    const int lane = tid & 63, wid = tid >> 6;
    const int widu = __builtin_amdgcn_readfirstlane(wid);
    const int wm = (wid >> 1) * 32, wn = (wid & 1) * 32;

    const int bid0 = blockIdx.x;
    const int bid = (bid0 & 7) * 68 + (bid0 >> 3);   // bijective: 544 = 8*68
    const bool isQ = bid >= 512;
    const int lb = isQ ? bid - 512 : bid;
    const size_t m0 = (size_t)(lb >> 2) * 64;
    const int n0 = (lb & 3) * 64;
    const float* A    = isQ ? query : key;
    const f16* BT     = isQ ? WTq : WTk;
    const float* bias = isQ ? bq : bk;

    // ---- B staging via global_load_lds (swizzled source, linear dest) ----
    const int o0 = wid * 1024 + (lane << 4);
    const int o1 = o0 + 4096;
    const int row0 = o0 >> 7, kb0 = (o0 & 127) ^ ((row0 & 7) << 4);
    const int row1 = o1 >> 7, kb1 = (o1 & 127) ^ ((row1 & 7) << 4);
    const char* b_t = (const char*)(BT + (size_t)n0 * K_DIM);   // row stride 1024 B

    auto GLOADB = [&](int buf, int t) {
        const int kb = t * 128;
        char* d0 = &smem[buf][2][widu * 1024];
        gload16(b_t + (size_t)row0 * 1024 + kb + kb0, d0);
        gload16(b_t + (size_t)row1 * 1024 + kb + kb1, d0 + 4096);
    };

    // ---- A staging: global f32 -> regs -> fp16 hi/lo -> swizzled ds_write ----
    const float* a_base = A + m0 * K_DIM;
    float4 areg[4];
    auto ALOAD = [&](int t) {
#pragma unroll
        for (int j = 0; j < 4; ++j) {
            const int fidx = j * 256 + tid;
            const int r = fidx >> 4, c16 = fidx & 15;
            areg[j] = *(const float4*)&a_base[(size_t)r * K_DIM + t * 64 + c16 * 4];
        }
    };
    auto AWRITE = [&](int buf) {
#pragma unroll
        for (int j = 0; j < 4; ++j) {
            const int fidx = j * 256 + tid;
            const int r = fidx >> 4, c16 = fidx & 15;
            const int byt = r * 128 + ((c16 * 8) ^ ((r & 7) << 4));
            f16 h0 = (f16)areg[j].x, h1 = (f16)areg[j].y, h2 = (f16)areg[j].z, h3 = (f16)areg[j].w;
            f16x4 hi = {h0, h1, h2, h3};
            f16x4 lo = {(f16)(areg[j].x - (float)h0), (f16)(areg[j].y - (float)h1),
                        (f16)(areg[j].z - (float)h2), (f16)(areg[j].w - (float)h3)};
            *(f16x4*)&smem[buf][0][byt] = hi;
            *(f16x4*)&smem[buf][1][byt] = lo;
        }
    };

    f32x4 acc[2][2] = {};
    const int fr = lane & 15, fgb = (lane >> 4) << 4;

    auto COMPUTE = [&](int buf) {
#pragma unroll
        for (int kk = 0; kk < 2; ++kk) {
            const int kbyte = kk * 64 + fgb;
            auto ld = [&](int arr, int row) -> f16x8 {
                int byt = ((row << 7) + kbyte) ^ ((row & 7) << 4);
                return *(const f16x8*)&smem[buf][arr][byt];
            };
            f16x8 ah0 = ld(0, wm + fr),      ah1 = ld(0, wm + 16 + fr);
            f16x8 al0 = ld(1, wm + fr),      al1 = ld(1, wm + 16 + fr);
            f16x8 b0  = ld(2, wn + fr),      b1  = ld(2, wn + 16 + fr);
            acc[0][0] = __builtin_amdgcn_mfma_f32_16x16x32_f16(ah0, b0, acc[0][0], 0, 0, 0);
            acc[0][1] = __builtin_amdgcn_mfma_f32_16x16x32_f16(ah0, b1, acc[0][1], 0, 0, 0);
            acc[1][0] = __builtin_amdgcn_mfma_f32_16x16x32_f16(ah1, b0, acc[1][0], 0, 0, 0);
            acc[1][1] = __builtin_amdgcn_mfma_f32_16x16x32_f16(ah1, b1, acc[1][1], 0, 0, 0);
            acc[0][0] = __builtin_amdgcn_mfma_f32_16x16x32_f16(al0, b0, acc[0][0], 0, 0, 0);
            acc[0][1] = __builtin_amdgcn_mfma_f32_16x16x32_f16(al0, b1, acc[0][1], 0, 0, 0);
            acc[1][0] = __builtin_amdgcn_mfma_f32_16x16x32_f16(al1, b0, acc[1][0], 0, 0, 0);
            acc[1][1] = __builtin_amdgcn_mfma_f32_16x16x32_f16(al1, b1, acc[1][1], 0, 0, 0);
        }
    };

    ALOAD(0);
    GLOADB(0, 0);
    AWRITE(0);
    __syncthreads();

    int buf = 0;
#pragma unroll 1
    for (int t = 0; t < 8; ++t) {
        if (t < 7) { ALOAD(t + 1); GLOADB(buf ^ 1, t + 1); }
        COMPUTE(buf);
        if (t < 7) { AWRITE(buf ^ 1); __syncthreads(); }
        buf ^= 1;
    }

    // C/D layout (m89): col = lane&15, row = (lane>>4)*4 + reg
    const int crow = (lane >> 4) * 4, ccol = lane & 15;
    if (isQ) {
#pragma unroll
        for (int f = 0; f < 2; ++f)
#pragma unroll
            for (int g = 0; g < 2; ++g) {
                int col = n0 + wn + g * 16 + ccol;
                float bv = bias[col];
#pragma unroll
                for (int r = 0; r < 4; ++r) {
                    size_t row = m0 + wm + f * 16 + crow + r;
                    float val = __expf(2.0f * (acc[f][g][r] + bv));
                    tq2[((size_t)(row & 7) * T_DIM + (row >> 3)) * H_DIM + col] = val;  // [b][t][h]
                }
            }
    } else {
        // stage into lt[b*8+s_off][68]; pitch 272B -> conflict-free gather reads
        float* lt = (float*)&smem[0][0][0];
#pragma unroll
        for (int f = 0; f < 2; ++f)
#pragma unroll
            for (int g = 0; g < 2; ++g) {
                int lcol = wn + g * 16 + ccol;
                float bv = bias[n0 + lcol];
#pragma unroll
                for (int r = 0; r < 4; ++r) {
                    int rr = wm + f * 16 + crow + r;         // rr = s_off*8 + b
                    lt[((rr & 7) * 8 + (rr >> 3)) * 68 + lcol] = __expf(2.0f * (acc[f][g][r] + bv));
                }
            }
        __syncthreads();
        // h-quad gather -> ktT4[b][h/4][s][4]; 8-lane 128B-contiguous store groups
        const int sbase = (int)(m0 >> 3);
        const int n0q = n0 >> 2;
#pragma unroll
        for (int p = 0; p < 4; ++p) {
            int c = p * 256 + tid;
            int s_off = c & 7, h4 = (c >> 3) & 15, b2 = c >> 7;
            float4 o = *(const float4*)&lt[(b2 * 8 + s_off) * 68 + h4 * 4];
            size_t f4idx = ((size_t)b2 * 64 + n0q + h4) * S_DIM + sbase + s_off;
            *(float4*)&ktT[f4idx * 4] = o;
        }
    }
}

// Fused scores+softmax: block = (b, t-pair), 1024 threads (16 waves), s = tid.
// 4-WAY rcp pairing (R25).  __launch_bounds__(1024, 2): force VGPR<=64 so
// TWO 16-wave blocks co-reside per CU (32 waves/CU) — double latency hiding.
__global__ __launch_bounds__(1024, 2) void scores_softmax_kernel(
    const float* __restrict__ ktT, const float* __restrict__ tq2,
    const float* __restrict__ v, float* __restrict__ out)
{
    __shared__ float redm[2][16], reds[2][16];
    const int tid = threadIdx.x, lane = tid & 63;
    const int wid = __builtin_amdgcn_readfirstlane(tid >> 6);   // 0..15
    const int bid = blockIdx.x;                   // [0,256)
    const int b = bid & 7;
    const int t0 = (bid >> 3) * 2;                // this block's 2 t-rows
    const int s = tid;                            // full row: s = 0..1023

    const float4* kb4 = (const float4*)ktT + (size_t)b * 64 * S_DIM + s;  // +h4*S per quad
    const float* q0p = tq2 + ((size_t)b * T_DIM + t0) * H_DIM;
    const float* q1p = q0p + H_DIM;

    float a0 = 0.f, a1 = 0.f;
#pragma unroll 8
    for (int h4 = 0; h4 < H_DIM / 4; ++h4) {
        float4 k4 = kb4[(size_t)h4 * S_DIM];              // coalesced 16B/lane
        float4 vv = *(const float4*)&v[h4 * 4];           // uniform dwordx4
        float4 q0 = *(const float4*)&q0p[h4 * 4];
        float4 q1 = *(const float4*)&q1p[h4 * 4];
        float A, B, C, D, AB, CD, n1, n2;
#define SC4(qq, aa) \
        A = fmaf(qq.x, k4.x, 1.0f); B = fmaf(qq.y, k4.y, 1.0f); \
        C = fmaf(qq.z, k4.z, 1.0f); D = fmaf(qq.w, k4.w, 1.0f); \
        AB = A * B; CD = C * D; \
        n1 = fmaf(vv.x, B, vv.y * A); \
        n2 = fmaf(vv.z, D, vv.w * C); \
        aa = fmaf(fmaf(n1, CD, n2 * AB), fast_rcp(AB * CD), aa);
        SC4(q0, a0)
        SC4(q1, a1)
#undef SC4
    }
    a0 *= -2.0f;
    a1 *= -2.0f;

    // ---- block softmax over s (1024 values per t-row) ----
    float m0 = a0, m1 = a1;
#pragma unroll
    for (int mm = 32; mm >= 1; mm >>= 1) {
        m0 = fmaxf(m0, __shfl_xor(m0, mm, 64));
        m1 = fmaxf(m1, __shfl_xor(m1, mm, 64));
    }
    if (lane == 0) { redm[0][wid] = m0; redm[1][wid] = m1; }
    __syncthreads();
    m0 = redm[0][0]; m1 = redm[1][0];
#pragma unroll
    for (int i = 1; i < 16; ++i) {
        m0 = fmaxf(m0, redm[0][i]);
        m1 = fmaxf(m1, redm[1][i]);
    }

    float e0 = __expf(a0 - m0), e1 = __expf(a1 - m1);
    float s0 = e0, s1 = e1;
#pragma unroll
    for (int mm = 32; mm >= 1; mm >>= 1) {
        s0 += __shfl_xor(s0, mm, 64);
        s1 += __shfl_xor(s1, mm, 64);
    }
    if (lane == 0) { reds[0][wid] = s0; reds[1][wid] = s1; }
    __syncthreads();
    s0 = 0.f; s1 = 0.f;
#pragma unroll
    for (int i = 0; i < 16; ++i) { s0 += reds[0][i]; s1 += reds[1][i]; }

    float* o = out + ((size_t)b * T_DIM + t0) * S_DIM + s;
    o[0]     = e0 * fast_rcp(s0);
    o[S_DIM] = e1 * fast_rcp(s1);
}

extern "C" void kernel_launch(void* const* d_in, const int* in_sizes, int n_in,
                              void* d_out, int out_size, void* d_ws, size_t ws_size,
                              hipStream_t stream)
{
    const float* key   = (const float*)d_in[0];
    const float* query = (const float*)d_in[1];
    const float* Wk    = (const float*)d_in[2];
    const float* bk    = (const float*)d_in[3];
    const float* Wq    = (const float*)d_in[4];
    const float* bq    = (const float*)d_in[5];
    const float* v     = (const float*)d_in[6];
    float* out = (float*)d_out;

    float* ktT    = (float*)d_ws;                       // B*(H/4)*S*4 f32 (8.39 MB) Ek h-quad
    float* tq2    = ktT + (size_t)B_DIM * H_DIM * S_DIM;// B*T*H f32  (0.52 MB)  Eq
    f16* WTk = (f16*)(tq2 + (size_t)B_DIM * T_DIM * H_DIM);     // H*K f16
    f16* WTq = WTk + (size_t)H_DIM * K_DIM;                     // H*K f16

    wconv_kernel<<<64, 256, 0, stream>>>(Wk, Wq, WTk, WTq);
    proj_gemm_all<<<544, 256, 0, stream>>>(key, WTk, bk, ktT, query, WTq, bq, tq2);
    scores_softmax_kernel<<<256, 1024, 0, stream>>>(ktT, tq2, v, out);
}